// Round 5
// baseline (241.923 us; speedup 1.0000x reference)
//
#include <hip/hip_runtime.h>

// GaussianPooling: fm[512,256,256] f32, keypoints[4096,2] int, out[4096,512] f32.
// 5x5 gaussian sigma=2, separable: k = g(dy)*g(dx)/s^2.
//
// R5: R4's pool stored outT[c][n] with random n -> 2M scattered dword stores,
// and blocks (c,q=0..7) on different XCDs interleaved partial writes into the
// SAME cache lines (16 n-slots/line span all octants) -> cross-XCD line
// ping-pong. Fix: store slot-compacted outT[c][q*4096+slot] (coalesced,
// disjoint per block); bucket builds a stable (i-ascending) list per octant
// via ballot-compaction plus inverse map pos[n]; final small transpose
// gathers outT[c][pos[n]] (near-sequential after sorting) and writes out
// coalesced.

#define NC  512
#define NH  256
#define NW  256
#define NKP 4096

#define OCT 8
#define SLICE_ROWS 36          // 32 + 2x2 halo
#define STR 260                // LDS row stride (floats): +4 keeps 16B align, rotates banks
#define OTSTRIDE (OCT * NKP)   // outT row stride in floats (32768; worst-case safe)

// ws layout (int32 offsets):
//   [0..8)                     cnt[8]
//   [16 .. 16+NKP)             pos[n] = q*NKP + slot
//   [8192 .. 8192+OCT*NKP)     packed lists (i | x<<12 | y<<20), stride NKP
//   int 65536 (byte 262144)    outT [NC][OTSTRIDE] floats (64 MB)
#define WS_POS_OFF_I  16
#define WS_LIST_OFF_I 8192
#define WS_OUTT_OFF_B 262144

// ---------------- bucket: 1 wave per octant, stable ballot compaction ----------------
__global__ __launch_bounds__(64) void bucket_kernel(
    const int* __restrict__ kp, unsigned* __restrict__ ws_i, int n_kp)
{
    const int q    = blockIdx.x;
    const int lane = threadIdx.x;
    int base = 0;
    for (int i0 = 0; i0 < n_kp; i0 += 64) {
        const int i = i0 + lane;
        int x = 0, y = 0;
        bool in = false;
        if (i < n_kp) {
            x = kp[2 * i + 0];
            y = kp[2 * i + 1];
            x = min(max(x, 2), NW - 3);
            y = min(max(y, 2), NH - 3);
            in = ((y >> 5) == q);
        }
        const unsigned long long m = __ballot(in);
        const int rank = __popcll(m & ((1ull << lane) - 1ull));
        if (in) {
            const int slot = base + rank;
            ws_i[WS_LIST_OFF_I + q * NKP + slot] =
                (unsigned)i | ((unsigned)x << 12) | ((unsigned)y << 20);
            ws_i[WS_POS_OFF_I + i] = (unsigned)(q * NKP + slot);
        }
        base += __popcll(m);
    }
    if (lane == 0) ws_i[q] = (unsigned)base;
}

// ---------------- pool: block = (channel, y-octant), plane slice in LDS ----------------
__global__ __launch_bounds__(256) void pool_kernel(
    const float* __restrict__ fm, const unsigned* __restrict__ ws_i,
    float* __restrict__ outT)
{
    __shared__ float plane[SLICE_ROWS * STR];   // 37,440 B

    const int c = blockIdx.x;
    const int q = blockIdx.y;
    const int t = threadIdx.x;
    const int ybase = q * 32 - 2;

    // stage rows [ybase, ybase+35] clamped to [0,255]; fully coalesced float4
    const float4* src = (const float4*)(fm + ((size_t)c << 16));
#pragma unroll
    for (int it = 0; it < (SLICE_ROWS * 64) / 256; ++it) {
        const int i = t + it * 256;
        const int row = i >> 6;
        const int col4 = i & 63;
        const int gr = ybase + row;
        if ((unsigned)gr < 256u) {
            float4 v = src[(gr << 6) + col4];
            *(float4*)&plane[row * STR + (col4 << 2)] = v;
        }
    }
    __syncthreads();

    // gaussian weights
    const float e1 = 0.8824969025845955f;  // exp(-1/8)
    const float e2 = 0.6065306597126334f;  // exp(-4/8)
    const float s  = 2.0f * (e1 + e2) + 1.0f;
    const float inv_s2 = 1.0f / (s * s);
    const float g[5] = {e2, e1, 1.0f, e1, e2};
    float gy[5];
#pragma unroll
    for (int i = 0; i < 5; i++) gy[i] = g[i] * inv_s2;

    const int cnt = (int)ws_i[q];
    const unsigned* list = ws_i + WS_LIST_OFF_I + q * NKP;
    float* orow = outT + (size_t)c * OTSTRIDE + q * NKP;

    for (int e = t; e < cnt; e += 256) {
        const unsigned pk = list[e];
        const int xc = (int)((pk >> 12) & 0xFFu);
        const int yc = (int)((pk >> 20) & 0xFFu);

        const int x0 = xc - 2;
        const int r  = x0 & 3;
        const int xa = x0 - r;
        float wx[8];
#pragma unroll
        for (int i = 0; i < 8; i++)
            wx[i] = (i >= r && i < r + 5) ? g[i - r] : 0.0f;

        const int lr0 = yc - (q << 5);   // plane row of (yc-2): 0..31
        float acc = 0.0f;
#pragma unroll
        for (int dy = 0; dy < 5; dy++) {
            const float* rowp = &plane[(lr0 + dy) * STR + xa];
            float4 a = *(const float4*)rowp;
            float4 b = *(const float4*)(rowp + 4);
            acc += gy[dy] * (a.x * wx[0] + a.y * wx[1] + a.z * wx[2] + a.w * wx[3]
                           + b.x * wx[4] + b.y * wx[5] + b.z * wx[6] + b.w * wx[7]);
        }
        orow[e] = acc;   // coalesced: thread t -> slot e = t + k*256
    }
}

// ---------------- final: out[n][c] = outT[c][pos[n]], tiled gather-transpose ----------------
__global__ __launch_bounds__(256) void outt_kernel(
    const float* __restrict__ outT, const unsigned* __restrict__ ws_i,
    float* __restrict__ out)
{
    __shared__ float tile[32][33];
    __shared__ unsigned pos_s[32];
    const int n0 = blockIdx.x * 32;
    const int c0 = blockIdx.y * 32;
    const int tx = threadIdx.x;   // 0..31
    const int ty = threadIdx.y;   // 0..7

    if (ty == 0) pos_s[tx] = ws_i[WS_POS_OFF_I + n0 + tx];
    __syncthreads();

#pragma unroll
    for (int k = 0; k < 32; k += 8)
        tile[ty + k][tx] = outT[(size_t)(c0 + ty + k) * OTSTRIDE + pos_s[tx]];
    __syncthreads();
#pragma unroll
    for (int k = 0; k < 32; k += 8)
        out[(size_t)(n0 + ty + k) * NC + c0 + tx] = tile[tx][ty + k];
}

// ---------------- fallback (round-1 direct kernel) ----------------
__global__ __launch_bounds__(256) void gpool_direct_kernel(
    const float* __restrict__ fm, const int* __restrict__ kp,
    float* __restrict__ out)
{
    const int n = blockIdx.x;
    const int t = threadIdx.x;

    int x = kp[2 * n + 0];
    int y = kp[2 * n + 1];
    x = min(max(x, 2), NW - 3);
    y = min(max(y, 2), NH - 3);

    const float e1 = 0.8824969025845955f;
    const float e2 = 0.6065306597126334f;
    const float s  = 2.0f * (e1 + e2) + 1.0f;
    const float inv_s2 = 1.0f / (s * s);
    float g[5] = {e2, e1, 1.0f, e1, e2};
    float gy[5];
#pragma unroll
    for (int i = 0; i < 5; i++) gy[i] = g[i] * inv_s2;

    const int x0 = x - 2;
    const int r  = x0 & 3;
    const int xa = x0 - r;
    float wx[8];
#pragma unroll
    for (int i = 0; i < 8; i++)
        wx[i] = (i >= r && i < r + 5) ? g[i - r] : 0.0f;

    const float* base0 = fm + ((size_t)t * NH + (y - 2)) * NW + xa;
    const float* base1 = fm + ((size_t)(t + 256) * NH + (y - 2)) * NW + xa;

    float acc0 = 0.0f, acc1 = 0.0f;
#pragma unroll
    for (int dy = 0; dy < 5; dy++) {
        const float4* p0 = (const float4*)(base0 + dy * NW);
        const float4* p1 = (const float4*)(base1 + dy * NW);
        float4 a0 = p0[0], b0 = p0[1], a1 = p1[0], b1 = p1[1];
        acc0 += gy[dy] * (a0.x * wx[0] + a0.y * wx[1] + a0.z * wx[2] + a0.w * wx[3]
                        + b0.x * wx[4] + b0.y * wx[5] + b0.z * wx[6] + b0.w * wx[7]);
        acc1 += gy[dy] * (a1.x * wx[0] + a1.y * wx[1] + a1.z * wx[2] + a1.w * wx[3]
                        + b1.x * wx[4] + b1.y * wx[5] + b1.z * wx[6] + b1.w * wx[7]);
    }

    out[(size_t)n * NC + t]       = acc0;
    out[(size_t)n * NC + t + 256] = acc1;
}

extern "C" void kernel_launch(void* const* d_in, const int* in_sizes, int n_in,
                              void* d_out, int out_size, void* d_ws, size_t ws_size,
                              hipStream_t stream)
{
    const float* fm  = (const float*)d_in[0];
    const int*   kp  = (const int*)d_in[1];
    float*       out = (float*)d_out;
    const int n_kp   = in_sizes[1] / 2;   // 4096

    const size_t need = WS_OUTT_OFF_B + (size_t)NC * OTSTRIDE * sizeof(float);
    if (ws_size >= need && n_kp == NKP) {
        unsigned* ws_i = (unsigned*)d_ws;
        float* outT    = (float*)((char*)d_ws + WS_OUTT_OFF_B);

        bucket_kernel<<<OCT, 64, 0, stream>>>(kp, ws_i, n_kp);

        dim3 pgrid(NC, OCT);
        pool_kernel<<<pgrid, 256, 0, stream>>>(fm, ws_i, outT);

        dim3 tgrid(NKP / 32, NC / 32);
        dim3 tblk(32, 8);
        outt_kernel<<<tgrid, tblk, 0, stream>>>(outT, ws_i, out);
    } else {
        gpool_direct_kernel<<<n_kp, 256, 0, stream>>>(fm, kp, out);
    }
}

// Round 6
// 210.747 us; speedup vs baseline: 1.1479x; 1.1479x over previous
//
#include <hip/hip_runtime.h>

// GaussianPooling: fm[512,256,256] f32, keypoints[4096,2] int, out[4096,512] f32.
// 5x5 gaussian sigma=2, separable: k = g(dy)*g(dx)/s^2.
//
// R6: R4/R5's hidden cost was the bucket kernel: 8 blocks only, sequential
// load rounds, latency-bound (~25-50 us!). Now: 16x256 one-shot bucketing
// with LDS histogram + global atomic range reservation (order-independent).
// Pool (block = channel x y-octant, 512 thr) stages a 36-row plane slice in
// LDS and writes out[n][c] directly (scattered dwords ~8 us chip-wide; saves
// the 24 MB outT round-trip and a launch). cnt[8] zeroed via hipMemsetAsync.

#define NC  512
#define NH  256
#define NW  256
#define NKP 4096

#define OCT 8
#define SLICE_ROWS 36          // 32 + 2x2 halo
#define STR 260                // LDS row stride (floats): +4 keeps 16B align, rotates banks

// ws layout (int32 offsets):
//   [0..8)                     cnt[8]  (zeroed by hipMemsetAsync)
//   [8192 .. 8192+OCT*NKP)     packed lists (i | x<<12 | y<<20), stride NKP
#define WS_LIST_OFF_I 8192

// ---------------- bucket: 1 kp/thread, LDS hist + global range reservation ----------------
__global__ __launch_bounds__(256) void bucket_kernel(
    const int* __restrict__ kp, unsigned* __restrict__ ws_i, int n_kp)
{
    __shared__ int hist[OCT];
    __shared__ int base[OCT];
    const int t = threadIdx.x;
    const int i = blockIdx.x * 256 + t;

    if (t < OCT) hist[t] = 0;
    __syncthreads();

    int q = 0, lr = 0;
    unsigned pk = 0;
    const bool valid = (i < n_kp);
    if (valid) {
        int x = kp[2 * i + 0];
        int y = kp[2 * i + 1];
        x = min(max(x, 2), NW - 3);
        y = min(max(y, 2), NH - 3);
        q  = y >> 5;
        lr = atomicAdd(&hist[q], 1);
        pk = (unsigned)i | ((unsigned)x << 12) | ((unsigned)y << 20);
    }
    __syncthreads();

    if (t < OCT) base[t] = atomicAdd((int*)&ws_i[t], hist[t]);
    __syncthreads();

    if (valid)
        ws_i[WS_LIST_OFF_I + q * NKP + base[q] + lr] = pk;
}

// ---------------- pool: block = (channel, y-octant), plane slice in LDS ----------------
__global__ __launch_bounds__(512) void pool_kernel(
    const float* __restrict__ fm, const unsigned* __restrict__ ws_i,
    float* __restrict__ out)
{
    __shared__ float plane[SLICE_ROWS * STR];   // 37,440 B -> 4 blocks/CU

    const int c = blockIdx.x;
    const int q = blockIdx.y;
    const int t = threadIdx.x;
    const int ybase = q * 32 - 2;

    // stage rows [ybase, ybase+35] clamped to [0,255]; fully coalesced float4
    const float4* src = (const float4*)(fm + ((size_t)c << 16));
#pragma unroll
    for (int it = 0; it < 5; ++it) {
        const int i = t + it * 512;
        if (i < SLICE_ROWS * 64) {
            const int row  = i >> 6;
            const int col4 = i & 63;
            const int gr   = ybase + row;
            if ((unsigned)gr < 256u) {
                float4 v = src[(gr << 6) + col4];
                *(float4*)&plane[row * STR + (col4 << 2)] = v;
            }
        }
    }
    __syncthreads();

    // gaussian weights
    const float e1 = 0.8824969025845955f;  // exp(-1/8)
    const float e2 = 0.6065306597126334f;  // exp(-4/8)
    const float s  = 2.0f * (e1 + e2) + 1.0f;
    const float inv_s2 = 1.0f / (s * s);
    const float g[5] = {e2, e1, 1.0f, e1, e2};
    float gy[5];
#pragma unroll
    for (int i = 0; i < 5; i++) gy[i] = g[i] * inv_s2;

    const int cnt = (int)ws_i[q];
    const unsigned* list = ws_i + WS_LIST_OFF_I + q * NKP;

    for (int e = t; e < cnt; e += 512) {
        const unsigned pk = list[e];
        const int n  = (int)(pk & 0xFFFu);
        const int xc = (int)((pk >> 12) & 0xFFu);
        const int yc = (int)((pk >> 20) & 0xFFu);

        const int x0 = xc - 2;
        const int r  = x0 & 3;
        const int xa = x0 - r;
        float wx[8];
#pragma unroll
        for (int i = 0; i < 8; i++)
            wx[i] = (i >= r && i < r + 5) ? g[i - r] : 0.0f;

        const int lr0 = yc - (q << 5);   // plane row of (yc-2): 0..31
        float acc = 0.0f;
#pragma unroll
        for (int dy = 0; dy < 5; dy++) {
            const float* rowp = &plane[(lr0 + dy) * STR + xa];
            float4 a = *(const float4*)rowp;
            float4 b = *(const float4*)(rowp + 4);
            acc += gy[dy] * (a.x * wx[0] + a.y * wx[1] + a.z * wx[2] + a.w * wx[3]
                           + b.x * wx[4] + b.y * wx[5] + b.z * wx[6] + b.w * wx[7]);
        }
        out[(size_t)n * NC + c] = acc;   // scattered dword; each (n,c) written once
    }
}

// ---------------- fallback (round-1 direct kernel) ----------------
__global__ __launch_bounds__(256) void gpool_direct_kernel(
    const float* __restrict__ fm, const int* __restrict__ kp,
    float* __restrict__ out)
{
    const int n = blockIdx.x;
    const int t = threadIdx.x;

    int x = kp[2 * n + 0];
    int y = kp[2 * n + 1];
    x = min(max(x, 2), NW - 3);
    y = min(max(y, 2), NH - 3);

    const float e1 = 0.8824969025845955f;
    const float e2 = 0.6065306597126334f;
    const float s  = 2.0f * (e1 + e2) + 1.0f;
    const float inv_s2 = 1.0f / (s * s);
    float g[5] = {e2, e1, 1.0f, e1, e2};
    float gy[5];
#pragma unroll
    for (int i = 0; i < 5; i++) gy[i] = g[i] * inv_s2;

    const int x0 = x - 2;
    const int r  = x0 & 3;
    const int xa = x0 - r;
    float wx[8];
#pragma unroll
    for (int i = 0; i < 8; i++)
        wx[i] = (i >= r && i < r + 5) ? g[i - r] : 0.0f;

    const float* base0 = fm + ((size_t)t * NH + (y - 2)) * NW + xa;
    const float* base1 = fm + ((size_t)(t + 256) * NH + (y - 2)) * NW + xa;

    float acc0 = 0.0f, acc1 = 0.0f;
#pragma unroll
    for (int dy = 0; dy < 5; dy++) {
        const float4* p0 = (const float4*)(base0 + dy * NW);
        const float4* p1 = (const float4*)(base1 + dy * NW);
        float4 a0 = p0[0], b0 = p0[1], a1 = p1[0], b1 = p1[1];
        acc0 += gy[dy] * (a0.x * wx[0] + a0.y * wx[1] + a0.z * wx[2] + a0.w * wx[3]
                        + b0.x * wx[4] + b0.y * wx[5] + b0.z * wx[6] + b0.w * wx[7]);
        acc1 += gy[dy] * (a1.x * wx[0] + a1.y * wx[1] + a1.z * wx[2] + a1.w * wx[3]
                        + b1.x * wx[4] + b1.y * wx[5] + b1.z * wx[6] + b1.w * wx[7]);
    }

    out[(size_t)n * NC + t]       = acc0;
    out[(size_t)n * NC + t + 256] = acc1;
}

extern "C" void kernel_launch(void* const* d_in, const int* in_sizes, int n_in,
                              void* d_out, int out_size, void* d_ws, size_t ws_size,
                              hipStream_t stream)
{
    const float* fm  = (const float*)d_in[0];
    const int*   kp  = (const int*)d_in[1];
    float*       out = (float*)d_out;
    const int n_kp   = in_sizes[1] / 2;   // 4096

    const size_t need = (WS_LIST_OFF_I + (size_t)OCT * NKP) * sizeof(unsigned);
    if (ws_size >= need && n_kp == NKP) {
        unsigned* ws_i = (unsigned*)d_ws;

        hipMemsetAsync(d_ws, 0, OCT * sizeof(unsigned), stream);   // zero cnt[8]

        bucket_kernel<<<(NKP + 255) / 256, 256, 0, stream>>>(kp, ws_i, n_kp);

        dim3 pgrid(NC, OCT);
        pool_kernel<<<pgrid, 512, 0, stream>>>(fm, ws_i, out);
    } else {
        gpool_direct_kernel<<<n_kp, 256, 0, stream>>>(fm, kp, out);
    }
}